// Round 9
// baseline (3188.062 us; speedup 1.0000x reference)
//
#include <hip/hip_runtime.h>

// Problem constants: T=1024, B=64, D=256, H=256, 4H=1024, D+H=512.

typedef _Float16 half2_t __attribute__((ext_vector_type(2)));
typedef _Float16 half4_t __attribute__((ext_vector_type(4)));
typedef _Float16 half8_t __attribute__((ext_vector_type(8)));
typedef float floatx4 __attribute__((ext_vector_type(4)));

__device__ __forceinline__ float fdot2(unsigned h, unsigned w, float acc) {
#if __has_builtin(__builtin_amdgcn_fdot2)
  return __builtin_amdgcn_fdot2(__builtin_bit_cast(half2_t, h),
                                __builtin_bit_cast(half2_t, w), acc, false);
#else
  half2_t a = __builtin_bit_cast(half2_t, h);
  half2_t b = __builtin_bit_cast(half2_t, w);
  return acc + (float)a[0] * (float)b[0] + (float)a[1] * (float)b[1];
#endif
}

__device__ __forceinline__ floatx4 mfma16x16x32(half8_t a, half8_t b, floatx4 c) {
#if __has_builtin(__builtin_amdgcn_mfma_f32_16x16x32_f16)
  return __builtin_amdgcn_mfma_f32_16x16x32_f16(a, b, c, 0, 0, 0);
#else
  half4_t alo = __builtin_shufflevector(a, a, 0, 1, 2, 3);
  half4_t ahi = __builtin_shufflevector(a, a, 4, 5, 6, 7);
  half4_t blo = __builtin_shufflevector(b, b, 0, 1, 2, 3);
  half4_t bhi = __builtin_shufflevector(b, b, 4, 5, 6, 7);
  c = __builtin_amdgcn_mfma_f32_16x16x16f16(alo, blo, c, 0, 0, 0);
  c = __builtin_amdgcn_mfma_f32_16x16x16f16(ahi, bhi, c, 0, 0, 0);
  return c;
#endif
}

__device__ __forceinline__ float sigm(float x) { return 1.f / (1.f + __expf(-x)); }
__device__ __forceinline__ float tanh_(float x) {
  float ax = fabsf(x);
  float e = __expf(-2.f * ax);
  float t = (1.f - e) / (1.f + e);
  return x < 0.f ? -t : t;
}

// ---------------------------------------------------------------------------
// K0: W [512][1024] f32 (row-major) -> WT [1024][512] fp16 (col-major of W).
// ---------------------------------------------------------------------------
__global__ __launch_bounds__(256) void k_transpose_w(const float* __restrict__ W,
                                                     _Float16* __restrict__ WT) {
  __shared__ float tile[64][65];
  const int bx = blockIdx.x & 15;
  const int by = blockIdx.x >> 4;
  const int c0 = bx * 64, r0 = by * 64;
  const int tid = threadIdx.x;
#pragma unroll
  for (int i = 0; i < 16; ++i) {
    int idx = tid + i * 256;
    int r = idx >> 6, c = idx & 63;
    tile[r][c] = W[(size_t)(r0 + r) * 1024 + c0 + c];
  }
  __syncthreads();
#pragma unroll
  for (int i = 0; i < 16; ++i) {
    int idx = tid + i * 256;
    int c = idx >> 6, r = idx & 63;
    WT[(size_t)(c0 + c) * 512 + r0 + r] = (_Float16)tile[r][c];
  }
}

// ---------------------------------------------------------------------------
// K1: Gx = X @ W[:256,:] + b, fp16 MFMA, f32 accum, fp16 out. BM=BN=128 BK=32.
// ---------------------------------------------------------------------------
__global__ __launch_bounds__(256) void k_gx_gemm(const float* __restrict__ X,
                                                 const _Float16* __restrict__ WT,
                                                 const float* __restrict__ bias,
                                                 _Float16* __restrict__ Gx) {
  const int nb = blockIdx.x & 7;
  const int mb = blockIdx.x >> 3;
  const int m0 = mb * 128, n0 = nb * 128;
  __shared__ __align__(16) _Float16 As[128 * 40];
  __shared__ __align__(16) _Float16 Bs[128 * 40];
  const int tid = threadIdx.x;
  const int wave = tid >> 6, lane = tid & 63;
  const int wm = (wave >> 1) * 64, wn = (wave & 1) * 64;
  const int lm = lane & 15, lg = lane >> 4;
  const int srow = tid >> 1, skh = (tid & 1) * 16;
  floatx4 acc[4][4] = {};
  for (int kt = 0; kt < 256; kt += 32) {
    __syncthreads();
    {
      const float* src = X + (size_t)(m0 + srow) * 256 + kt + skh;
      float4 f0 = ((const float4*)src)[0];
      float4 f1 = ((const float4*)src)[1];
      float4 f2 = ((const float4*)src)[2];
      float4 f3 = ((const float4*)src)[3];
      half8_t h0 = {(_Float16)f0.x, (_Float16)f0.y, (_Float16)f0.z, (_Float16)f0.w,
                    (_Float16)f1.x, (_Float16)f1.y, (_Float16)f1.z, (_Float16)f1.w};
      half8_t h1 = {(_Float16)f2.x, (_Float16)f2.y, (_Float16)f2.z, (_Float16)f2.w,
                    (_Float16)f3.x, (_Float16)f3.y, (_Float16)f3.z, (_Float16)f3.w};
      *(half8_t*)&As[srow * 40 + skh] = h0;
      *(half8_t*)&As[srow * 40 + skh + 8] = h1;
      const _Float16* bsrc = WT + (size_t)(n0 + srow) * 512 + kt + skh;
      half8_t b0 = ((const half8_t*)bsrc)[0];
      half8_t b1 = ((const half8_t*)bsrc)[1];
      *(half8_t*)&Bs[srow * 40 + skh] = b0;
      *(half8_t*)&Bs[srow * 40 + skh + 8] = b1;
    }
    __syncthreads();
    half8_t af[4], bf[4];
#pragma unroll
    for (int mf = 0; mf < 4; ++mf)
      af[mf] = *(const half8_t*)&As[(wm + mf * 16 + lm) * 40 + lg * 8];
#pragma unroll
    for (int nf = 0; nf < 4; ++nf)
      bf[nf] = *(const half8_t*)&Bs[(wn + nf * 16 + lm) * 40 + lg * 8];
#pragma unroll
    for (int mf = 0; mf < 4; ++mf)
#pragma unroll
      for (int nf = 0; nf < 4; ++nf)
        acc[mf][nf] = mfma16x16x32(af[mf], bf[nf], acc[mf][nf]);
  }
#pragma unroll
  for (int mf = 0; mf < 4; ++mf) {
#pragma unroll
    for (int nf = 0; nf < 4; ++nf) {
      const int gm = m0 + wm + mf * 16 + lg * 4;
      const int gn = n0 + wn + nf * 16 + lm;
      const float bv = bias[gn];
#pragma unroll
      for (int i = 0; i < 4; ++i)
        Gx[(size_t)(gm + i) * 1024 + gn] = (_Float16)(acc[mf][nf][i] + bv);
    }
  }
}

// ---------------------------------------------------------------------------
// K2: persistent per-batch LSTM recurrence. 64 blocks (1/CU), 512 threads.
// Thread owns gate columns {tid, tid+512}.
//
// HISTORY: R2-R8 proved the VGPR allocator is pinned at 128 for this kernel
// (launch_bounds / waves_per_eu / num_vgpr / static-LDS / asm-pin all left
// VGPR_Count=128); staged weights were rematerialized (R2-R6) or scratch-
// spilled (R8), re-streaming 368KB/block/step through the CU cache port =
// 1.7-2.0us/step.
//
// R9: bypass the VGPR budget entirely -- stage weight rows 0..183 into
// AGPRs with explicit `v_accvgpr_write_b32` ("=a" asm). gfx950 has a
// unified 512-reg file; AGPR class is outside the 128-VGPR heuristic.
// In-loop, each dword is pulled back with a VOLATILE `v_accvgpr_read_b32`
// (volatile so LICM cannot hoist 184 reads into live VGPRs) and fed to
// v_dot2_f32_f16. AGPR 184 + arch-VGPR ~70 <= 256 keeps 2 waves/SIMD.
//
//   rows 0..183   -> 184 AGPR dwords per thread (2 cols x 23 uint4)
//   rows 184..255 -> static LDS wl[1024][9] uint4 = 144KB; 36-dword column
//                    stride -> conflict-free (SQ_LDS_BANK_CONFLICT=0, R3-R8).
// hx in LDS as fp16x2, uniform-address broadcast reads.
// Gx/noise prefetched one step ahead.
// ---------------------------------------------------------------------------
__global__ __attribute__((amdgpu_flat_work_group_size(512, 512),
                          amdgpu_waves_per_eu(2, 2))) void
k_lstm(const _Float16* __restrict__ Gx, const _Float16* __restrict__ WT,
       const float* __restrict__ noise, const float* __restrict__ beta_p,
       float* __restrict__ out) {
  __shared__ __align__(16) uint4 wl[1024 * 9];  // 144KB weight rows 184..255
  __shared__ float gates[1024];                 // 4KB
  __shared__ unsigned hx2[128];                 // 512B: 256 fp16 h values

  const int b = blockIdx.x;
  const int tid = threadIdx.x;
  const float beta = beta_p[0];
  const int c0 = tid, c1 = tid + 512;

  // Stage weights. WT row offset +256 = h-part of the fused matrix.
  const uint4* p0 = (const uint4*)(WT + (size_t)c0 * 512 + 256);
  const uint4* p1 = (const uint4*)(WT + (size_t)c1 * 512 + 256);

  // 184 AGPR-resident weight dwords (asm-defined, outside VGPR budget).
  unsigned aw0[92], aw1[92];
#pragma unroll
  for (int i = 0; i < 23; ++i) {
    uint4 t = p0[i];
    asm volatile("v_accvgpr_write_b32 %0, %1" : "=a"(aw0[4 * i + 0]) : "v"(t.x));
    asm volatile("v_accvgpr_write_b32 %0, %1" : "=a"(aw0[4 * i + 1]) : "v"(t.y));
    asm volatile("v_accvgpr_write_b32 %0, %1" : "=a"(aw0[4 * i + 2]) : "v"(t.z));
    asm volatile("v_accvgpr_write_b32 %0, %1" : "=a"(aw0[4 * i + 3]) : "v"(t.w));
  }
#pragma unroll
  for (int i = 0; i < 23; ++i) {
    uint4 t = p1[i];
    asm volatile("v_accvgpr_write_b32 %0, %1" : "=a"(aw1[4 * i + 0]) : "v"(t.x));
    asm volatile("v_accvgpr_write_b32 %0, %1" : "=a"(aw1[4 * i + 1]) : "v"(t.y));
    asm volatile("v_accvgpr_write_b32 %0, %1" : "=a"(aw1[4 * i + 2]) : "v"(t.z));
    asm volatile("v_accvgpr_write_b32 %0, %1" : "=a"(aw1[4 * i + 3]) : "v"(t.w));
  }
  uint4* wlp0 = wl + c0 * 9;
  uint4* wlp1 = wl + c1 * 9;
#pragma unroll
  for (int i = 0; i < 9; ++i) wlp0[i] = p0[23 + i];
#pragma unroll
  for (int i = 0; i < 9; ++i) wlp1[i] = p1[23 + i];
  if (tid < 128) hx2[tid] = 0u;
  float cx = 0.f, hlast = 0.f;
  __syncthreads();

  const _Float16* gp0 = Gx + (size_t)b * 1024 + c0;
  const _Float16* gp1 = Gx + (size_t)b * 1024 + c1;
  const float* nzp = noise + (size_t)b * 256 + (tid & 255);
  float* outp = out + (size_t)b * 256 + tid;  // only used when tid<256

  // Prefetch step 0.
  float g0 = (float)gp0[0];
  float g1 = (float)gp1[0];
  float nz = nzp[0];

  for (int t = 0; t < 1024; ++t) {
    // Prefetch step t+1 (hides under the fdot2 phase).
    float g0n = 0.f, g1n = 0.f, nzn = 0.f;
    if (t < 1023) {
      g0n = (float)gp0[65536];
      g1n = (float)gp1[65536];
      nzn = nzp[16384];
    }

    float a0e = 0.f, a0o = 0.f, a1e = 0.f, a1o = 0.f;
    // AGPR-resident rows 0..183: chunk i = rows 8i..8i+7.
#pragma unroll
    for (int i = 0; i < 23; ++i) {
      uint4 h4 = *(const uint4*)&hx2[i * 4];  // wave-uniform -> LDS broadcast
      unsigned wx, wy, wz, ww;
      asm volatile("v_accvgpr_read_b32 %0, %1" : "=v"(wx) : "a"(aw0[4 * i + 0]));
      asm volatile("v_accvgpr_read_b32 %0, %1" : "=v"(wy) : "a"(aw0[4 * i + 1]));
      asm volatile("v_accvgpr_read_b32 %0, %1" : "=v"(wz) : "a"(aw0[4 * i + 2]));
      asm volatile("v_accvgpr_read_b32 %0, %1" : "=v"(ww) : "a"(aw0[4 * i + 3]));
      a0e = fdot2(h4.x, wx, a0e);
      a0o = fdot2(h4.y, wy, a0o);
      a0e = fdot2(h4.z, wz, a0e);
      a0o = fdot2(h4.w, ww, a0o);
      asm volatile("v_accvgpr_read_b32 %0, %1" : "=v"(wx) : "a"(aw1[4 * i + 0]));
      asm volatile("v_accvgpr_read_b32 %0, %1" : "=v"(wy) : "a"(aw1[4 * i + 1]));
      asm volatile("v_accvgpr_read_b32 %0, %1" : "=v"(wz) : "a"(aw1[4 * i + 2]));
      asm volatile("v_accvgpr_read_b32 %0, %1" : "=v"(ww) : "a"(aw1[4 * i + 3]));
      a1e = fdot2(h4.x, wx, a1e);
      a1o = fdot2(h4.y, wy, a1o);
      a1e = fdot2(h4.z, wz, a1e);
      a1o = fdot2(h4.w, ww, a1o);
    }
    // LDS-resident rows 184..255: chunks 23..31.
#pragma unroll
    for (int i = 0; i < 9; ++i) {
      uint4 h4 = *(const uint4*)&hx2[92 + i * 4];
      uint4 wa = wlp0[i];
      uint4 wb = wlp1[i];
      a0e = fdot2(h4.x, wa.x, a0e);
      a0o = fdot2(h4.y, wa.y, a0o);
      a0e = fdot2(h4.z, wa.z, a0e);
      a0o = fdot2(h4.w, wa.w, a0o);
      a1e = fdot2(h4.x, wb.x, a1e);
      a1o = fdot2(h4.y, wb.y, a1o);
      a1e = fdot2(h4.z, wb.z, a1e);
      a1o = fdot2(h4.w, wb.w, a1o);
    }
    gates[c0] = a0e + a0o + g0;
    gates[c1] = a1e + a1o + g1;
    __syncthreads();  // gates ready; all hx2 reads for step t done

    if (tid < 256) {
      float f = sigm(gates[tid]);
      float ii = sigm(gates[tid + 256]);
      float gg = tanh_(gates[tid + 512]);
      float oo = sigm(gates[tid + 768]);
      cx = f * cx + ii * gg;
      float h = oo * tanh_(cx) + beta * nz;
      hlast = h;
      outp[0] = h;
      ((_Float16*)hx2)[tid] = (_Float16)h;  // publish hx for step t+1
    }
    g0 = g0n; g1 = g1n; nz = nzn;
    gp0 += 65536; gp1 += 65536; nzp += 16384; outp += 16384;
    __syncthreads();  // hx2 ready
  }

  if (tid < 256) {
    out[(size_t)16777216 + (size_t)b * 256 + tid] = hlast;       // final hx
    out[(size_t)16777216 + 16384 + (size_t)b * 256 + tid] = cx;  // final cx
  }
}

// ---------------------------------------------------------------------------
extern "C" void kernel_launch(void* const* d_in, const int* in_sizes, int n_in,
                              void* d_out, int out_size, void* d_ws, size_t ws_size,
                              hipStream_t stream) {
  const float* X = (const float*)d_in[0];      // [1024,64,256]
  const float* W = (const float*)d_in[1];      // [512,1024]
  const float* bias = (const float*)d_in[2];   // [1024]
  const float* beta = (const float*)d_in[3];   // [1]
  const float* noise = (const float*)d_in[4];  // [1024,64,256]
  float* out = (float*)d_out;

  char* ws = (char*)d_ws;
  _Float16* Gx = (_Float16*)ws;                        // 128 MB
  _Float16* WT = (_Float16*)(ws + (size_t)134217728);  // 1 MB

  k_transpose_w<<<128, 256, 0, stream>>>(W, WT);
  k_gx_gemm<<<4096, 256, 0, stream>>>(X, WT, bias, Gx);
  k_lstm<<<64, 512, 0, stream>>>(Gx, WT, noise, beta, out);
}

// Round 10
// 2927.859 us; speedup vs baseline: 1.0889x; 1.0889x over previous
//
#include <hip/hip_runtime.h>

// Problem constants: T=1024, B=64, D=256, H=256, 4H=1024, D+H=512.

typedef _Float16 half2_t __attribute__((ext_vector_type(2)));
typedef _Float16 half4_t __attribute__((ext_vector_type(4)));
typedef _Float16 half8_t __attribute__((ext_vector_type(8)));
typedef float floatx4 __attribute__((ext_vector_type(4)));

__device__ __forceinline__ floatx4 mfma16x16x32(half8_t a, half8_t b, floatx4 c) {
#if __has_builtin(__builtin_amdgcn_mfma_f32_16x16x32_f16)
  return __builtin_amdgcn_mfma_f32_16x16x32_f16(a, b, c, 0, 0, 0);
#else
  half4_t alo = __builtin_shufflevector(a, a, 0, 1, 2, 3);
  half4_t ahi = __builtin_shufflevector(a, a, 4, 5, 6, 7);
  half4_t blo = __builtin_shufflevector(b, b, 0, 1, 2, 3);
  half4_t bhi = __builtin_shufflevector(b, b, 4, 5, 6, 7);
  c = __builtin_amdgcn_mfma_f32_16x16x16f16(alo, blo, c, 0, 0, 0);
  c = __builtin_amdgcn_mfma_f32_16x16x16f16(ahi, bhi, c, 0, 0, 0);
  return c;
#endif
}

__device__ __forceinline__ float sigm(float x) { return 1.f / (1.f + __expf(-x)); }
__device__ __forceinline__ float tanh_(float x) {
  float ax = fabsf(x);
  float e = __expf(-2.f * ax);
  float t = (1.f - e) / (1.f + e);
  return x < 0.f ? -t : t;
}

// ---------------------------------------------------------------------------
// K0: W [512][1024] f32 (row-major) -> WT [1024][512] fp16 (col-major of W).
// ---------------------------------------------------------------------------
__global__ __launch_bounds__(256) void k_transpose_w(const float* __restrict__ W,
                                                     _Float16* __restrict__ WT) {
  __shared__ float tile[64][65];
  const int bx = blockIdx.x & 15;
  const int by = blockIdx.x >> 4;
  const int c0 = bx * 64, r0 = by * 64;
  const int tid = threadIdx.x;
#pragma unroll
  for (int i = 0; i < 16; ++i) {
    int idx = tid + i * 256;
    int r = idx >> 6, c = idx & 63;
    tile[r][c] = W[(size_t)(r0 + r) * 1024 + c0 + c];
  }
  __syncthreads();
#pragma unroll
  for (int i = 0; i < 16; ++i) {
    int idx = tid + i * 256;
    int c = idx >> 6, r = idx & 63;
    WT[(size_t)(c0 + c) * 512 + r0 + r] = (_Float16)tile[r][c];
  }
}

// ---------------------------------------------------------------------------
// K1: Gx = X @ W[:256,:] + b, fp16 MFMA, f32 accum, fp16 out. BM=BN=128 BK=32.
// (Passing since R1 -> proves the 16x16x32_f16 A/B/C fragment layouts used
//  below in k_lstm.)
// ---------------------------------------------------------------------------
__global__ __launch_bounds__(256) void k_gx_gemm(const float* __restrict__ X,
                                                 const _Float16* __restrict__ WT,
                                                 const float* __restrict__ bias,
                                                 _Float16* __restrict__ Gx) {
  const int nb = blockIdx.x & 7;
  const int mb = blockIdx.x >> 3;
  const int m0 = mb * 128, n0 = nb * 128;
  __shared__ __align__(16) _Float16 As[128 * 40];
  __shared__ __align__(16) _Float16 Bs[128 * 40];
  const int tid = threadIdx.x;
  const int wave = tid >> 6, lane = tid & 63;
  const int wm = (wave >> 1) * 64, wn = (wave & 1) * 64;
  const int lm = lane & 15, lg = lane >> 4;
  const int srow = tid >> 1, skh = (tid & 1) * 16;
  floatx4 acc[4][4] = {};
  for (int kt = 0; kt < 256; kt += 32) {
    __syncthreads();
    {
      const float* src = X + (size_t)(m0 + srow) * 256 + kt + skh;
      float4 f0 = ((const float4*)src)[0];
      float4 f1 = ((const float4*)src)[1];
      float4 f2 = ((const float4*)src)[2];
      float4 f3 = ((const float4*)src)[3];
      half8_t h0 = {(_Float16)f0.x, (_Float16)f0.y, (_Float16)f0.z, (_Float16)f0.w,
                    (_Float16)f1.x, (_Float16)f1.y, (_Float16)f1.z, (_Float16)f1.w};
      half8_t h1 = {(_Float16)f2.x, (_Float16)f2.y, (_Float16)f2.z, (_Float16)f2.w,
                    (_Float16)f3.x, (_Float16)f3.y, (_Float16)f3.z, (_Float16)f3.w};
      *(half8_t*)&As[srow * 40 + skh] = h0;
      *(half8_t*)&As[srow * 40 + skh + 8] = h1;
      const _Float16* bsrc = WT + (size_t)(n0 + srow) * 512 + kt + skh;
      half8_t b0 = ((const half8_t*)bsrc)[0];
      half8_t b1 = ((const half8_t*)bsrc)[1];
      *(half8_t*)&Bs[srow * 40 + skh] = b0;
      *(half8_t*)&Bs[srow * 40 + skh + 8] = b1;
    }
    __syncthreads();
    half8_t af[4], bf[4];
#pragma unroll
    for (int mf = 0; mf < 4; ++mf)
      af[mf] = *(const half8_t*)&As[(wm + mf * 16 + lm) * 40 + lg * 8];
#pragma unroll
    for (int nf = 0; nf < 4; ++nf)
      bf[nf] = *(const half8_t*)&Bs[(wn + nf * 16 + lm) * 40 + lg * 8];
#pragma unroll
    for (int mf = 0; mf < 4; ++mf)
#pragma unroll
      for (int nf = 0; nf < 4; ++nf)
        acc[mf][nf] = mfma16x16x32(af[mf], bf[nf], acc[mf][nf]);
  }
#pragma unroll
  for (int mf = 0; mf < 4; ++mf) {
#pragma unroll
    for (int nf = 0; nf < 4; ++nf) {
      const int gm = m0 + wm + mf * 16 + lg * 4;
      const int gn = n0 + wn + nf * 16 + lm;
      const float bv = bias[gn];
#pragma unroll
      for (int i = 0; i < 4; ++i)
        Gx[(size_t)(gm + i) * 1024 + gn] = (_Float16)(acc[mf][nf][i] + bv);
    }
  }
}

// ---------------------------------------------------------------------------
// K1b: pre-swizzle Wh into MFMA B-fragment order.
// WB[((w*8+n)*8+c)*64 + l] = uint4 covering col = w*128+n*16+(l&15),
// k = c*32+(l>>4)*8 .. +7 (fp16 pairs). Source WT col-major: contiguous. 
// ---------------------------------------------------------------------------
__global__ __launch_bounds__(256) void k_prep_frags(const _Float16* __restrict__ WT,
                                                    uint4* __restrict__ WB) {
  const int gid = blockIdx.x * 256 + threadIdx.x;  // 0..32767
  const int l = gid & 63;
  const int c = (gid >> 6) & 7;
  const int n = (gid >> 9) & 7;
  const int w = gid >> 12;
  const int col = w * 128 + n * 16 + (l & 15);
  const int k0 = c * 32 + (l >> 4) * 8;
  WB[gid] = *(const uint4*)(WT + (size_t)col * 512 + 256 + k0);
}

// ---------------------------------------------------------------------------
// K2: persistent per-batch LSTM recurrence via MFMA. 64 blocks, 512 threads.
//
// ROOT CAUSE (R9 recount): R5's 1.66us/step == 328 ds_read_b128/CU/step x
// ~10cyc (LDS ISSUE-bound on per-thread uniform h-broadcasts), not weight
// streaming. Fix: MFMA matvec -- h is read once per WAVE as the A-fragment
// (8 b128/wave/step, rows 1..15 zero), weights are B-fragments:
//   tiles 0..3 (per wave): 128 dwords in asm AGPRs (+ <=128 VGPR = 256 =
//     exactly 2 waves/SIMD; fits the allocator's proven 128-VGPR cap)
//   tiles 4..7: streamed from L2 each step (frag-ordered WB buffer,
//     perfectly coalesced; 2MB/XCD/step ~= 465ns; 3-slot chunk pipeline;
//     t-opaque base pointer defeats LICM hoisting)
// C row 0 (lanes 0..15, reg 0) = the 16 gate preactivations per tile.
// ---------------------------------------------------------------------------
#define RES_MFMA(c, n)                                                        \
  {                                                                           \
    unsigned qx, qy, qz, qw;                                                  \
    asm volatile("v_accvgpr_read_b32 %0, %1" : "=v"(qx) : "a"(aw[(n * 8 + c) * 4 + 0])); \
    asm volatile("v_accvgpr_read_b32 %0, %1" : "=v"(qy) : "a"(aw[(n * 8 + c) * 4 + 1])); \
    asm volatile("v_accvgpr_read_b32 %0, %1" : "=v"(qz) : "a"(aw[(n * 8 + c) * 4 + 2])); \
    asm volatile("v_accvgpr_read_b32 %0, %1" : "=v"(qw) : "a"(aw[(n * 8 + c) * 4 + 3])); \
    uint4 q = {qx, qy, qz, qw};                                               \
    acc[n] = mfma16x16x32(af, __builtin_bit_cast(half8_t, q), acc[n]);        \
  }

#define LSTM_CHUNK(c, Scons, Sprod, DOLOAD)                                   \
  {                                                                           \
    if (DOLOAD) {                                                             \
      Sprod[0] = sbase[0 * 512 + (c + 2) * 64];                               \
      Sprod[1] = sbase[1 * 512 + (c + 2) * 64];                               \
      Sprod[2] = sbase[2 * 512 + (c + 2) * 64];                               \
      Sprod[3] = sbase[3 * 512 + (c + 2) * 64];                               \
    }                                                                         \
    half8_t af = *(const half8_t*)(hbase + c * 32);                           \
    RES_MFMA(c, 0)                                                            \
    RES_MFMA(c, 1)                                                            \
    RES_MFMA(c, 2)                                                            \
    RES_MFMA(c, 3)                                                            \
    acc[4] = mfma16x16x32(af, __builtin_bit_cast(half8_t, Scons[0]), acc[4]); \
    acc[5] = mfma16x16x32(af, __builtin_bit_cast(half8_t, Scons[1]), acc[5]); \
    acc[6] = mfma16x16x32(af, __builtin_bit_cast(half8_t, Scons[2]), acc[6]); \
    acc[7] = mfma16x16x32(af, __builtin_bit_cast(half8_t, Scons[3]), acc[7]); \
  }

__global__ __attribute__((amdgpu_flat_work_group_size(512, 512),
                          amdgpu_waves_per_eu(2, 2))) void
k_lstm(const _Float16* __restrict__ Gx, const uint4* __restrict__ WB,
       const float* __restrict__ noise, const float* __restrict__ beta_p,
       float* __restrict__ out) {
  __shared__ float gates[1024];                  // 4KB: Wh.h preactivations
  __shared__ __align__(16) _Float16 hxPad[512];  // [0..255]=h, [256..511]=zeros
  __shared__ uint4 lds_force[5120];              // 80KB pad: force 1 block/CU

  const int b = blockIdx.x;
  const int tid = threadIdx.x;
  const int l = tid & 63;
  const int w = tid >> 6;
  const float beta = beta_p[0];

  if (beta_p == nullptr) lds_force[0] = uint4{0, 0, 0, 0};  // keep pad alive

  if (tid < 256) {
    hxPad[tid] = (_Float16)0.f;        // h0 = 0
    hxPad[256 + tid] = (_Float16)0.f;  // zero region for A rows 1..15
  }

  // Stage resident B-fragments (tiles 0..3) into 128 AGPRs.
  const uint4* wbl = WB + w * 4096 + l;
  unsigned aw[128];
#pragma unroll
  for (int n = 0; n < 4; ++n) {
#pragma unroll
    for (int c = 0; c < 8; ++c) {
      uint4 t = wbl[n * 512 + c * 64];
      const int i = (n * 8 + c) * 4;
      asm volatile("v_accvgpr_write_b32 %0, %1" : "=a"(aw[i + 0]) : "v"(t.x));
      asm volatile("v_accvgpr_write_b32 %0, %1" : "=a"(aw[i + 1]) : "v"(t.y));
      asm volatile("v_accvgpr_write_b32 %0, %1" : "=a"(aw[i + 2]) : "v"(t.z));
      asm volatile("v_accvgpr_write_b32 %0, %1" : "=a"(aw[i + 3]) : "v"(t.w));
    }
  }

  // A-fragment base: lanes with (l&15)==0 read h; all others read the zero
  // region (rows 1..15 of A = 0 -> C rows 1..15 = 0, no garbage).
  const _Float16* hbase = hxPad + (((l & 15) == 0) ? 0 : 256) + (l >> 4) * 8;
  const uint4* sbase = wbl + 4 * 512;  // streamed tiles 4..7

  float cx = 0.f, hlast = 0.f;
  const floatx4 fzero = {0.f, 0.f, 0.f, 0.f};
  __syncthreads();

  for (int t = 0; t < 1024; ++t) {
    // Defeat LICM on streamed weight loads: make sbase loop-variant/opaque.
    {
      unsigned lo = (unsigned)(uintptr_t)sbase;
      unsigned hi = (unsigned)((uintptr_t)sbase >> 32);
      asm volatile("" : "+v"(lo), "+v"(hi));
      sbase = (const uint4*)(((uintptr_t)hi << 32) | lo);
    }
    const size_t base = (size_t)t * 64 + b;

    // Prefetch this step's Gx + noise (consumed after the MFMA phase).
    float gx0 = 0.f, gx1 = 0.f, gx2 = 0.f, gx3 = 0.f, nz = 0.f;
    if (tid < 256) {
      const _Float16* gp = Gx + base * 1024 + tid;
      gx0 = (float)gp[0];
      gx1 = (float)gp[256];
      gx2 = (float)gp[512];
      gx3 = (float)gp[768];
      nz = noise[base * 256 + tid];
    }

    floatx4 acc[8];
#pragma unroll
    for (int n = 0; n < 8; ++n) acc[n] = fzero;

    // Stream pipeline prologue: chunks 0,1 of tiles 4..7.
    uint4 S0[4], S1[4], S2[4];
    S0[0] = sbase[0 * 512 + 0 * 64];
    S0[1] = sbase[1 * 512 + 0 * 64];
    S0[2] = sbase[2 * 512 + 0 * 64];
    S0[3] = sbase[3 * 512 + 0 * 64];
    S1[0] = sbase[0 * 512 + 1 * 64];
    S1[1] = sbase[1 * 512 + 1 * 64];
    S1[2] = sbase[2 * 512 + 1 * 64];
    S1[3] = sbase[3 * 512 + 1 * 64];

    LSTM_CHUNK(0, S0, S2, 1)
    LSTM_CHUNK(1, S1, S0, 1)
    LSTM_CHUNK(2, S2, S1, 1)
    LSTM_CHUNK(3, S0, S2, 1)
    LSTM_CHUNK(4, S1, S0, 1)
    LSTM_CHUNK(5, S2, S1, 1)
    LSTM_CHUNK(6, S0, S2, 0)
    LSTM_CHUNK(7, S1, S0, 0)

    // C row 0 -> gates: lane j<16 reg0 of tile n = col w*128+n*16+j.
#pragma unroll
    for (int n = 0; n < 8; ++n)
      if (l < 16) gates[w * 128 + n * 16 + l] = acc[n][0];
    __syncthreads();

    if (tid < 256) {
      float f = sigm(gates[tid] + gx0);
      float ii = sigm(gates[tid + 256] + gx1);
      float gg = tanh_(gates[tid + 512] + gx2);
      float oo = sigm(gates[tid + 768] + gx3);
      cx = f * cx + ii * gg;
      float h = oo * tanh_(cx) + beta * nz;
      hlast = h;
      out[base * 256 + tid] = h;
      hxPad[tid] = (_Float16)h;  // publish h for step t+1
    }
    __syncthreads();
  }

  if (tid < 256) {
    out[(size_t)16777216 + (size_t)b * 256 + tid] = hlast;       // final hx
    out[(size_t)16777216 + 16384 + (size_t)b * 256 + tid] = cx;  // final cx
  }
}

// ---------------------------------------------------------------------------
extern "C" void kernel_launch(void* const* d_in, const int* in_sizes, int n_in,
                              void* d_out, int out_size, void* d_ws, size_t ws_size,
                              hipStream_t stream) {
  const float* X = (const float*)d_in[0];      // [1024,64,256]
  const float* W = (const float*)d_in[1];      // [512,1024]
  const float* bias = (const float*)d_in[2];   // [1024]
  const float* beta = (const float*)d_in[3];   // [1]
  const float* noise = (const float*)d_in[4];  // [1024,64,256]
  float* out = (float*)d_out;

  char* ws = (char*)d_ws;
  _Float16* Gx = (_Float16*)ws;                        // 128 MB
  _Float16* WT = (_Float16*)(ws + (size_t)134217728);  // 1 MB
  uint4* WB = (uint4*)(ws + (size_t)135266304);        // 512 KB frag-ordered Wh

  k_transpose_w<<<128, 256, 0, stream>>>(W, WT);
  k_prep_frags<<<128, 256, 0, stream>>>(WT, WB);
  k_gx_gemm<<<4096, 256, 0, stream>>>(X, WT, bias, Gx);
  k_lstm<<<64, 512, 0, stream>>>(Gx, WB, noise, beta, out);
}